// Round 7
// baseline (163.351 us; speedup 1.0000x reference)
//
#include <hip/hip_runtime.h>

// SlotEquivariantHead: 16-step digit scan; per step MLP 162->256->256->96, 32 carry fed back.
// Round 7 = R4 structure (93us best: swapped-operand MFMA, natural read-then-MFMA order)
// minus the W3-in-LDS re-reads:
//  (1) P3 runs on 6 waves (2 m-halves x 3 nt-pairs); W3 frags live in registers (loaded once).
//  (2) Waves 6,7 stage XAB(p+1) during P3 (removes serial staging block + pf registers).
//  (3) Biases come from LDS broadcast reads (frees 28 regs to pay for w3f; no spills).
// 8 waves/block, 64 rows/block, grid 256, 2 waves/SIMD.

typedef __attribute__((ext_vector_type(8))) short bf16x8;
typedef __attribute__((ext_vector_type(4))) float f32x4;
typedef __attribute__((ext_vector_type(2))) unsigned int u32x2;
typedef __attribute__((ext_vector_type(4))) unsigned int u32x4;

#define LDS_XAB 0        // 16 KB: [64 r][128 k] bf16, 256B rows, swz chunk^(r&15)
#define LDS_XC  16384    //  8 KB: [64 r][64 k]  bf16, 128B rows, swz chunk^(r&7)
#define LDS_H1  24576    // 32 KB: [64 r][256 n] bf16, 512B rows, swz chunk^(r&15)
#define LDS_H2  57344    // 32 KB
#define LDS_B1  90112    // 1 KB f32 b1
#define LDS_B2  91136    // 1 KB f32 b2
#define LDS_B3  92160    // 384 B f32 b3
#define LDS_TOTAL 92672

__device__ inline unsigned short f32_to_bf16(float f) {
  unsigned int u = __builtin_bit_cast(unsigned int, f);
  u += 0x7FFFu + ((u >> 16) & 1u);
  return (unsigned short)(u >> 16);
}

__device__ inline unsigned int cvt_pk_bf16(float lo, float hi) {
  unsigned int r;
  asm("v_cvt_pk_bf16_f32 %0, %1, %2" : "=v"(r) : "v"(lo), "v"(hi));
  return r;
}

// Pack W1 (rows permuted, K-pad 192), W2 (256x256), W3 (256x96) into bf16 MFMA fragment
// layout: frag(kk,nt): lane l, elem j <- W[kk*32 + (l>>4)*8 + j][nt*16 + (l&15)].
// W1 row permutation k' -> source row: [0,128) a|b direct; [128,160) carry = 130+(k'-128);
// {160,161} op = 128+(k'-160); [162,192) zero.  (matches XC tail = [carry|op|pad])
__global__ void pack_weights_kernel(const float* __restrict__ W1,
                                    const float* __restrict__ W2,
                                    const float* __restrict__ W3,
                                    unsigned short* __restrict__ wp) {
  int idx = blockIdx.x * 256 + threadIdx.x;
  if (idx >= 139264) return;
  int j, lane, frag, nt, kk, k, n;
  float v = 0.0f;
  if (idx < 49152) {
    int e = idx;
    j = e & 7; lane = (e >> 3) & 63; frag = e >> 9;
    nt = frag % 16; kk = frag / 16;
    k = kk * 32 + ((lane >> 4) << 3) + j;
    n = nt * 16 + (lane & 15);
    int ksrc;
    if (k < 128)      ksrc = k;
    else if (k < 160) ksrc = 130 + (k - 128);   // carry rows
    else if (k < 162) ksrc = 128 + (k - 160);   // op rows
    else              ksrc = -1;                 // zero pad
    v = (ksrc >= 0) ? W1[ksrc * 256 + n] : 0.0f;
  } else if (idx < 114688) {
    int e = idx - 49152;
    j = e & 7; lane = (e >> 3) & 63; frag = e >> 9;
    nt = frag % 16; kk = frag / 16;
    k = kk * 32 + ((lane >> 4) << 3) + j;
    n = nt * 16 + (lane & 15);
    v = W2[k * 256 + n];
  } else {
    int e = idx - 114688;
    j = e & 7; lane = (e >> 3) & 63; frag = e >> 9;
    nt = frag % 6; kk = frag / 6;
    k = kk * 32 + ((lane >> 4) << 3) + j;
    n = nt * 16 + (lane & 15);
    v = W3[k * 96 + n];
  }
  wp[idx] = f32_to_bf16(v);
}

__global__ __launch_bounds__(512, 2) void scan_kernel(
    const float* __restrict__ Ain, const float* __restrict__ Bin,
    const float* __restrict__ Op,
    const float* __restrict__ b1, const float* __restrict__ b2,
    const float* __restrict__ b3,
    const unsigned short* __restrict__ wp,
    float* __restrict__ out) {
  extern __shared__ char lds[];

  const int tid  = threadIdx.x;
  const int wave = tid >> 6, lane = tid & 63;
  const int lcol = lane & 15;      // batch-row within tile
  const int q    = lane >> 4;      // k-quad for reads; n-quad for writes
  const int row0 = blockIdx.x * 64;
  const int n3 = wave % 3;         // P3: nt-pair index (valid for wave<6)
  const int mh = wave / 3;         // P3: m-half (valid for wave<6)

  // ---- persistent weight fragments: P1/P2 wave owns nt = wave*2 + n (n = 0,1);
  //      P3 wave (wave<6) owns nt-pair {2*n3, 2*n3+1} over all kk.
  bf16x8 w1f[12], w2f[16], w3f[16];
  {
    const char* wb = (const char*)wp;
    #pragma unroll
    for (int kk = 0; kk < 6; ++kk)
      #pragma unroll
      for (int n = 0; n < 2; ++n)
        w1f[kk*2+n] = *(const bf16x8*)(wb + (size_t)(kk*16 + wave*2 + n)*1024 + lane*16);
    const char* wb2 = wb + 98304;
    #pragma unroll
    for (int kk = 0; kk < 8; ++kk)
      #pragma unroll
      for (int n = 0; n < 2; ++n)
        w2f[kk*2+n] = *(const bf16x8*)(wb2 + (size_t)(kk*16 + wave*2 + n)*1024 + lane*16);
    const char* wb3 = wb + 229376;
    #pragma unroll
    for (int kk = 0; kk < 8; ++kk)
      #pragma unroll
      for (int jn = 0; jn < 2; ++jn)
        w3f[kk*2+jn] = *(const bf16x8*)(wb3 + (size_t)(kk*6 + n3*2 + jn)*1024 + lane*16);
  }

  // ---- biases -> LDS (f32, broadcast-read at acc init)
  if (tid < 256) ((float*)(lds + LDS_B1))[tid] = b1[tid];
  else           ((float*)(lds + LDS_B2))[tid - 256] = b2[tid - 256];
  if (tid < 96)  ((float*)(lds + LDS_B3))[tid] = b3[tid];

  // ---- XC init: k 0..31 carry=0, 32..33 op, 34..63 zero
  for (int i = tid; i < 4096; i += 512) {
    int r = i >> 6, kx = i & 63;
    unsigned short v = 0;
    if (kx == 32 || kx == 33) v = f32_to_bf16(Op[(size_t)(row0 + r)*2 + (kx - 32)]);
    int chunk = kx >> 3, within = (kx & 7) * 2;
    *(unsigned short*)(lds + LDS_XC + r*128 + ((chunk ^ (r & 7)) << 4) + within) = v;
  }

  // ---- p=0 stage (all threads): thread -> row srow, 16 floats at part*16 of [a|b] row
  {
    const int part = tid & 7;
    const int srow = tid >> 3;
    const float* srcp = (part < 4 ? Ain : Bin) + (size_t)(row0 + srow)*1024 + (part & 3)*16;
    float4 pv[4];
    #pragma unroll
    for (int jj = 0; jj < 4; ++jj) pv[jj] = *(const float4*)(srcp + jj*4);
    unsigned int u[8];
    #pragma unroll
    for (int jj = 0; jj < 4; ++jj) {
      u[jj*2]   = cvt_pk_bf16(pv[jj].x, pv[jj].y);
      u[jj*2+1] = cvt_pk_bf16(pv[jj].z, pv[jj].w);
    }
    u32x4 t0 = {u[0],u[1],u[2],u[3]}, t1 = {u[4],u[5],u[6],u[7]};
    *(u32x4*)(lds + LDS_XAB + srow*256 + (((part*2)   ^ (srow & 15)) << 4)) = t0;
    *(u32x4*)(lds + LDS_XAB + srow*256 + (((part*2+1) ^ (srow & 15)) << 4)) = t1;
  }
  __syncthreads();

  #pragma unroll 1
  for (int p = 0; p < 16; ++p) {
    // ============ phase 1: Y^T = W1^T @ X^T -> relu -> H1 [64r][256n] ============
    {
      f32x4 acc[2][4];
      {
        f32x4 bA = *(const f32x4*)(lds + LDS_B1 + (((wave*2+0)*16 + q*4) << 2));
        f32x4 bB = *(const f32x4*)(lds + LDS_B1 + (((wave*2+1)*16 + q*4) << 2));
        #pragma unroll
        for (int mi = 0; mi < 4; ++mi) { acc[0][mi] = bA; acc[1][mi] = bB; }
      }
      #pragma unroll
      for (int m = 0; m < 4; ++m) {
        const int r = m*16 + lcol;
        bf16x8 xf[6];
        #pragma unroll
        for (int kk = 0; kk < 4; ++kk)
          xf[kk] = *(const bf16x8*)(lds + LDS_XAB + r*256 + (((4*kk + q) ^ lcol) << 4));
        #pragma unroll
        for (int kk = 0; kk < 2; ++kk)
          xf[4+kk] = *(const bf16x8*)(lds + LDS_XC + r*128 + (((4*kk + q) ^ (lcol & 7)) << 4));
        __builtin_amdgcn_s_setprio(1);
        #pragma unroll
        for (int kk = 0; kk < 6; ++kk) {
          acc[0][m] = __builtin_amdgcn_mfma_f32_16x16x32_bf16(w1f[kk*2+0], xf[kk], acc[0][m], 0,0,0);
          acc[1][m] = __builtin_amdgcn_mfma_f32_16x16x32_bf16(w1f[kk*2+1], xf[kk], acc[1][m], 0,0,0);
        }
        __builtin_amdgcn_s_setprio(0);
      }
      #pragma unroll
      for (int n = 0; n < 2; ++n) {
        const int nbyte = (wave*2+n)*32 + q*8;
        const int chunk = nbyte >> 4, within = nbyte & 15;
        #pragma unroll
        for (int m = 0; m < 4; ++m) {
          const int r = m*16 + lcol;
          float v0 = fmaxf(acc[n][m][0], 0.f);
          float v1 = fmaxf(acc[n][m][1], 0.f);
          float v2 = fmaxf(acc[n][m][2], 0.f);
          float v3 = fmaxf(acc[n][m][3], 0.f);
          u32x2 t; t.x = cvt_pk_bf16(v0, v1); t.y = cvt_pk_bf16(v2, v3);
          *(u32x2*)(lds + LDS_H1 + r*512 + ((chunk ^ lcol) << 4) + within) = t;
        }
      }
    }
    __syncthreads();  // B1

    // ============ phase 2: W2^T @ H1^T -> relu -> H2 ============
    {
      f32x4 acc[2][4];
      {
        f32x4 bA = *(const f32x4*)(lds + LDS_B2 + (((wave*2+0)*16 + q*4) << 2));
        f32x4 bB = *(const f32x4*)(lds + LDS_B2 + (((wave*2+1)*16 + q*4) << 2));
        #pragma unroll
        for (int mi = 0; mi < 4; ++mi) { acc[0][mi] = bA; acc[1][mi] = bB; }
      }
      #pragma unroll
      for (int m = 0; m < 4; ++m) {
        const int r = m*16 + lcol;
        bf16x8 hf[8];
        #pragma unroll
        for (int kk = 0; kk < 8; ++kk)
          hf[kk] = *(const bf16x8*)(lds + LDS_H1 + r*512 + (((4*kk + q) ^ lcol) << 4));
        __builtin_amdgcn_s_setprio(1);
        #pragma unroll
        for (int kk = 0; kk < 8; ++kk) {
          acc[0][m] = __builtin_amdgcn_mfma_f32_16x16x32_bf16(w2f[kk*2+0], hf[kk], acc[0][m], 0,0,0);
          acc[1][m] = __builtin_amdgcn_mfma_f32_16x16x32_bf16(w2f[kk*2+1], hf[kk], acc[1][m], 0,0,0);
        }
        __builtin_amdgcn_s_setprio(0);
      }
      #pragma unroll
      for (int n = 0; n < 2; ++n) {
        const int nbyte = (wave*2+n)*32 + q*8;
        const int chunk = nbyte >> 4, within = nbyte & 15;
        #pragma unroll
        for (int m = 0; m < 4; ++m) {
          const int r = m*16 + lcol;
          float v0 = fmaxf(acc[n][m][0], 0.f);
          float v1 = fmaxf(acc[n][m][1], 0.f);
          float v2 = fmaxf(acc[n][m][2], 0.f);
          float v3 = fmaxf(acc[n][m][3], 0.f);
          u32x2 t; t.x = cvt_pk_bf16(v0, v1); t.y = cvt_pk_bf16(v2, v3);
          *(u32x2*)(lds + LDS_H2 + r*512 + ((chunk ^ lcol) << 4) + within) = t;
        }
      }
    }
    __syncthreads();  // B2

    // ============ phase 3 (waves 0..5): W3^T @ H2^T, W3 in regs;
    //              waves 6,7: stage XAB(p+1) from global ============
    if (wave < 6) {
      f32x4 acc3[2][2];   // [mi][jn]
      {
        f32x4 c0 = *(const f32x4*)(lds + LDS_B3 + (((n3*2+0)*16 + q*4) << 2));
        f32x4 c1 = *(const f32x4*)(lds + LDS_B3 + (((n3*2+1)*16 + q*4) << 2));
        acc3[0][0] = c0; acc3[0][1] = c1; acc3[1][0] = c0; acc3[1][1] = c1;
      }
      #pragma unroll
      for (int mi = 0; mi < 2; ++mi) {
        const int r = (mh*2 + mi)*16 + lcol;
        bf16x8 hf[8];
        #pragma unroll
        for (int kk = 0; kk < 8; ++kk)
          hf[kk] = *(const bf16x8*)(lds + LDS_H2 + r*512 + (((4*kk + q) ^ lcol) << 4));
        __builtin_amdgcn_s_setprio(1);
        #pragma unroll
        for (int kk = 0; kk < 8; ++kk) {
          acc3[mi][0] = __builtin_amdgcn_mfma_f32_16x16x32_bf16(w3f[kk*2+0], hf[kk], acc3[mi][0], 0,0,0);
          acc3[mi][1] = __builtin_amdgcn_mfma_f32_16x16x32_bf16(w3f[kk*2+1], hf[kk], acc3[mi][1], 0,0,0);
        }
        __builtin_amdgcn_s_setprio(0);
      }
      #pragma unroll
      for (int jn = 0; jn < 2; ++jn) {
        const int nt = n3*2 + jn;
        #pragma unroll
        for (int mi = 0; mi < 2; ++mi) {
          const int r = (mh*2 + mi)*16 + lcol;
          if (nt < 4) {
            float4 o;
            o.x = acc3[mi][jn][0]; o.y = acc3[mi][jn][1];
            o.z = acc3[mi][jn][2]; o.w = acc3[mi][jn][3];
            *(float4*)&out[(size_t)(row0 + r)*1024 + p*64 + nt*16 + q*4] = o;
          } else {
            const int kbyte = (nt-4)*32 + q*8;          // carry channels at XC k 0..31
            const int chunk = kbyte >> 4, within = kbyte & 15;
            u32x2 t;
            t.x = cvt_pk_bf16(acc3[mi][jn][0], acc3[mi][jn][1]);
            t.y = cvt_pk_bf16(acc3[mi][jn][2], acc3[mi][jn][3]);
            *(u32x2*)(lds + LDS_XC + r*128 + ((chunk ^ (r & 7)) << 4) + within) = t;
          }
        }
      }
    } else if (p < 15) {
      // waves 6,7: JIT stage of XAB(p+1). thread -> (row sr, array half), 64 floats.
      const int th = tid - 384;          // 0..127
      const int sr = th & 63, half = th >> 6;
      const float* sp = (half ? Bin : Ain) + (size_t)(row0 + sr)*1024 + (p+1)*64;
      float4 v[16];
      #pragma unroll
      for (int j = 0; j < 16; ++j) v[j] = *(const float4*)(sp + j*4);
      #pragma unroll
      for (int j2 = 0; j2 < 8; ++j2) {
        u32x4 t;
        t.x = cvt_pk_bf16(v[2*j2].x,   v[2*j2].y);
        t.y = cvt_pk_bf16(v[2*j2].z,   v[2*j2].w);
        t.z = cvt_pk_bf16(v[2*j2+1].x, v[2*j2+1].y);
        t.w = cvt_pk_bf16(v[2*j2+1].z, v[2*j2+1].w);
        *(u32x4*)(lds + LDS_XAB + sr*256 + (((half*8 + j2) ^ (sr & 15)) << 4)) = t;
      }
    }
    __syncthreads();  // B3
  }
}

extern "C" void kernel_launch(void* const* d_in, const int* in_sizes, int n_in,
                              void* d_out, int out_size, void* d_ws, size_t ws_size,
                              hipStream_t stream) {
  const float* bias_a = (const float*)d_in[0];
  const float* bias_b = (const float*)d_in[1];
  const float* op     = (const float*)d_in[2];
  const float* W1     = (const float*)d_in[3];
  const float* b1     = (const float*)d_in[4];
  const float* W2     = (const float*)d_in[5];
  const float* b2     = (const float*)d_in[6];
  const float* W3     = (const float*)d_in[7];
  const float* b3     = (const float*)d_in[8];
  float* out = (float*)d_out;
  unsigned short* wp = (unsigned short*)d_ws;

  hipFuncSetAttribute((const void*)scan_kernel,
                      hipFuncAttributeMaxDynamicSharedMemorySize, LDS_TOTAL);

  pack_weights_kernel<<<544, 256, 0, stream>>>(W1, W2, W3, wp);
  scan_kernel<<<256, 512, LDS_TOTAL, stream>>>(bias_a, bias_b, op, b1, b2, b3, wp, out);
}

// Round 8
// 118.374 us; speedup vs baseline: 1.3800x; 1.3800x over previous
//
#include <hip/hip_runtime.h>

// SlotEquivariantHead: 16-step digit scan; per step MLP 162->256->256->96, 32 carry fed back.
// Round 8 = R4 (proven 93us: swapped-operand MFMA Y^T = W^T@X^T, natural schedule) +
// K-split phase 3: 8 waves = 2 K-halves x (2 m-pairs x 2 nt-triples); W3 frags in regs
// (12 frags = 48 regs/wave), partials exchanged in f32 through the dead H1 region.
// Kills the 192KB/pos W3 LDS re-read (largest single LDS item). Biases moved to LDS
// (-28 regs) to fund w3f. Weight regs total 160; transient reads capped at 4 frags.
// 8 waves/block, 64 rows/block, grid 256, 2 waves/SIMD.

typedef __attribute__((ext_vector_type(8))) short bf16x8;
typedef __attribute__((ext_vector_type(4))) float f32x4;
typedef __attribute__((ext_vector_type(2))) unsigned int u32x2;
typedef __attribute__((ext_vector_type(4))) unsigned int u32x4;

#define LDS_XAB 0        // 16 KB: [64 r][128 k] bf16, 256B rows, swz chunk^(r&15)
#define LDS_XC  16384    //  8 KB: [64 r][64 k]  bf16, 128B rows, swz chunk^(r&7)
#define LDS_H1  24576    // 32 KB: [64 r][256 n] bf16 (P3 reuses first 24KB as f32 scratch)
#define LDS_H2  57344    // 32 KB
#define LDS_B1  90112    // 1 KB f32 b1
#define LDS_B2  91136    // 1 KB f32 b2
#define LDS_B3  92160    // 384 B f32 b3
#define LDS_TOTAL 92672

__device__ inline unsigned short f32_to_bf16(float f) {
  unsigned int u = __builtin_bit_cast(unsigned int, f);
  u += 0x7FFFu + ((u >> 16) & 1u);
  return (unsigned short)(u >> 16);
}

__device__ inline unsigned int cvt_pk_bf16(float lo, float hi) {
  unsigned int r;
  asm("v_cvt_pk_bf16_f32 %0, %1, %2" : "=v"(r) : "v"(lo), "v"(hi));
  return r;
}

// Pack W1 (rows permuted, K-pad 192), W2 (256x256), W3 (256x96) into bf16 MFMA fragment
// layout: frag(kk,nt): lane l, elem j <- W[kk*32 + (l>>4)*8 + j][nt*16 + (l&15)].
// W1 row permutation k' -> source row: [0,128) a|b direct; [128,160) carry = 130+(k'-128);
// {160,161} op = 128+(k'-160); [162,192) zero.  (matches XC tail = [carry|op|pad])
__global__ void pack_weights_kernel(const float* __restrict__ W1,
                                    const float* __restrict__ W2,
                                    const float* __restrict__ W3,
                                    unsigned short* __restrict__ wp) {
  int idx = blockIdx.x * 256 + threadIdx.x;
  if (idx >= 139264) return;
  int j, lane, frag, nt, kk, k, n;
  float v = 0.0f;
  if (idx < 49152) {
    int e = idx;
    j = e & 7; lane = (e >> 3) & 63; frag = e >> 9;
    nt = frag % 16; kk = frag / 16;
    k = kk * 32 + ((lane >> 4) << 3) + j;
    n = nt * 16 + (lane & 15);
    int ksrc;
    if (k < 128)      ksrc = k;
    else if (k < 160) ksrc = 130 + (k - 128);   // carry rows
    else if (k < 162) ksrc = 128 + (k - 160);   // op rows
    else              ksrc = -1;                 // zero pad
    v = (ksrc >= 0) ? W1[ksrc * 256 + n] : 0.0f;
  } else if (idx < 114688) {
    int e = idx - 49152;
    j = e & 7; lane = (e >> 3) & 63; frag = e >> 9;
    nt = frag % 16; kk = frag / 16;
    k = kk * 32 + ((lane >> 4) << 3) + j;
    n = nt * 16 + (lane & 15);
    v = W2[k * 256 + n];
  } else {
    int e = idx - 114688;
    j = e & 7; lane = (e >> 3) & 63; frag = e >> 9;
    nt = frag % 6; kk = frag / 6;
    k = kk * 32 + ((lane >> 4) << 3) + j;
    n = nt * 16 + (lane & 15);
    v = W3[k * 96 + n];
  }
  wp[idx] = f32_to_bf16(v);
}

__global__ __launch_bounds__(512, 2) void scan_kernel(
    const float* __restrict__ Ain, const float* __restrict__ Bin,
    const float* __restrict__ Op,
    const float* __restrict__ b1, const float* __restrict__ b2,
    const float* __restrict__ b3,
    const unsigned short* __restrict__ wp,
    float* __restrict__ out) {
  extern __shared__ char lds[];

  const int tid  = threadIdx.x;
  const int wave = tid >> 6, lane = tid & 63;
  const int lcol = lane & 15;      // batch-row within tile
  const int q    = lane >> 4;      // k-quad for reads; n-quad for writes
  const int row0 = blockIdx.x * 64;
  // P3 K-split roles: kh = K-half, sub3 -> (m-pair mh3, nt-triple np3)
  const int kh   = wave & 1;
  const int sub3 = wave >> 1;
  const int mh3  = sub3 >> 1, np3 = sub3 & 1;

  // ---- persistent weight fragments:
  //  P1/P2: wave owns nt = wave*2 + n (n = 0,1)
  //  P3:    wave owns kk in [4kh,4kh+4) x nt in [3np3, 3np3+3): 12 frags
  bf16x8 w1f[12], w2f[16], w3f[12];
  {
    const char* wb = (const char*)wp;
    #pragma unroll
    for (int kk = 0; kk < 6; ++kk)
      #pragma unroll
      for (int n = 0; n < 2; ++n)
        w1f[kk*2+n] = *(const bf16x8*)(wb + (size_t)(kk*16 + wave*2 + n)*1024 + lane*16);
    const char* wb2 = wb + 98304;
    #pragma unroll
    for (int kk = 0; kk < 8; ++kk)
      #pragma unroll
      for (int n = 0; n < 2; ++n)
        w2f[kk*2+n] = *(const bf16x8*)(wb2 + (size_t)(kk*16 + wave*2 + n)*1024 + lane*16);
    const char* wb3 = wb + 229376;
    #pragma unroll
    for (int kk = 0; kk < 4; ++kk)
      #pragma unroll
      for (int j = 0; j < 3; ++j)
        w3f[kk*3+j] = *(const bf16x8*)(wb3 + (size_t)((kh*4+kk)*6 + np3*3 + j)*1024 + lane*16);
  }

  // ---- biases -> LDS (f32, broadcast-read at acc init / P3 finish)
  if (tid < 256) ((float*)(lds + LDS_B1))[tid] = b1[tid];
  else           ((float*)(lds + LDS_B2))[tid - 256] = b2[tid - 256];
  if (tid < 96)  ((float*)(lds + LDS_B3))[tid] = b3[tid];

  // ---- XC init: k 0..31 carry=0, 32..33 op, 34..63 zero
  for (int i = tid; i < 4096; i += 512) {
    int r = i >> 6, kx = i & 63;
    unsigned short v = 0;
    if (kx == 32 || kx == 33) v = f32_to_bf16(Op[(size_t)(row0 + r)*2 + (kx - 32)]);
    int chunk = kx >> 3, within = (kx & 7) * 2;
    *(unsigned short*)(lds + LDS_XC + r*128 + ((chunk ^ (r & 7)) << 4) + within) = v;
  }

  // ---- a/b staging: thread covers row srow, 16 floats at part*16 of the 128-col [a|b] row
  const int part = tid & 7;
  const int srow = tid >> 3;
  const float* srcp = (part < 4 ? Ain : Bin) + (size_t)(row0 + srow)*1024 + (part & 3)*16;
  float4 pf[4];

  {  // p=0 synchronous stage + p=1 prefetch
    #pragma unroll
    for (int jj = 0; jj < 4; ++jj) pf[jj] = *(const float4*)(srcp + jj*4);
    unsigned int u[8];
    #pragma unroll
    for (int jj = 0; jj < 4; ++jj) {
      u[jj*2]   = cvt_pk_bf16(pf[jj].x, pf[jj].y);
      u[jj*2+1] = cvt_pk_bf16(pf[jj].z, pf[jj].w);
    }
    u32x4 t0 = {u[0],u[1],u[2],u[3]}, t1 = {u[4],u[5],u[6],u[7]};
    *(u32x4*)(lds + LDS_XAB + srow*256 + (((part*2)   ^ (srow & 15)) << 4)) = t0;
    *(u32x4*)(lds + LDS_XAB + srow*256 + (((part*2+1) ^ (srow & 15)) << 4)) = t1;
    #pragma unroll
    for (int jj = 0; jj < 4; ++jj) pf[jj] = *(const float4*)(srcp + 64 + jj*4);
  }
  __syncthreads();

  const f32x4 zero4 = {0.f, 0.f, 0.f, 0.f};

  #pragma unroll 1
  for (int p = 0; p < 16; ++p) {
    // ============ phase 1: Y^T = W1^T @ X^T -> relu -> H1 [64r][256n] ============
    {
      f32x4 acc[2][4];
      {
        f32x4 bA = *(const f32x4*)(lds + LDS_B1 + (((wave*2+0)*16 + q*4) << 2));
        f32x4 bB = *(const f32x4*)(lds + LDS_B1 + (((wave*2+1)*16 + q*4) << 2));
        #pragma unroll
        for (int mi = 0; mi < 4; ++mi) { acc[0][mi] = bA; acc[1][mi] = bB; }
      }
      #pragma unroll
      for (int m = 0; m < 4; ++m) {
        const int r = m*16 + lcol;
        bf16x8 xf[6];
        #pragma unroll
        for (int kk = 0; kk < 4; ++kk)
          xf[kk] = *(const bf16x8*)(lds + LDS_XAB + r*256 + (((4*kk + q) ^ lcol) << 4));
        #pragma unroll
        for (int kk = 0; kk < 2; ++kk)
          xf[4+kk] = *(const bf16x8*)(lds + LDS_XC + r*128 + (((4*kk + q) ^ (lcol & 7)) << 4));
        __builtin_amdgcn_s_setprio(1);
        #pragma unroll
        for (int kk = 0; kk < 6; ++kk) {
          acc[0][m] = __builtin_amdgcn_mfma_f32_16x16x32_bf16(w1f[kk*2+0], xf[kk], acc[0][m], 0,0,0);
          acc[1][m] = __builtin_amdgcn_mfma_f32_16x16x32_bf16(w1f[kk*2+1], xf[kk], acc[1][m], 0,0,0);
        }
        __builtin_amdgcn_s_setprio(0);
      }
      #pragma unroll
      for (int n = 0; n < 2; ++n) {
        const int nbyte = (wave*2+n)*32 + q*8;
        const int chunk = nbyte >> 4, within = nbyte & 15;
        #pragma unroll
        for (int m = 0; m < 4; ++m) {
          const int r = m*16 + lcol;
          float v0 = fmaxf(acc[n][m][0], 0.f);
          float v1 = fmaxf(acc[n][m][1], 0.f);
          float v2 = fmaxf(acc[n][m][2], 0.f);
          float v3 = fmaxf(acc[n][m][3], 0.f);
          u32x2 t; t.x = cvt_pk_bf16(v0, v1); t.y = cvt_pk_bf16(v2, v3);
          *(u32x2*)(lds + LDS_H1 + r*512 + ((chunk ^ lcol) << 4) + within) = t;
        }
      }
    }
    __syncthreads();  // B1

    // ---- stage XAB(p+1) from pf; prefetch p+2 ----
    if (p < 15) {
      unsigned int u[8];
      #pragma unroll
      for (int jj = 0; jj < 4; ++jj) {
        u[jj*2]   = cvt_pk_bf16(pf[jj].x, pf[jj].y);
        u[jj*2+1] = cvt_pk_bf16(pf[jj].z, pf[jj].w);
      }
      u32x4 t0 = {u[0],u[1],u[2],u[3]}, t1 = {u[4],u[5],u[6],u[7]};
      *(u32x4*)(lds + LDS_XAB + srow*256 + (((part*2)   ^ (srow & 15)) << 4)) = t0;
      *(u32x4*)(lds + LDS_XAB + srow*256 + (((part*2+1) ^ (srow & 15)) << 4)) = t1;
      if (p < 14) {
        const float* s2 = srcp + (p+2)*64;
        #pragma unroll
        for (int jj = 0; jj < 4; ++jj) pf[jj] = *(const float4*)(s2 + jj*4);
      }
    }

    // ============ phase 2: W2^T @ H1^T -> relu -> H2 ============
    {
      f32x4 acc[2][4];
      {
        f32x4 bA = *(const f32x4*)(lds + LDS_B2 + (((wave*2+0)*16 + q*4) << 2));
        f32x4 bB = *(const f32x4*)(lds + LDS_B2 + (((wave*2+1)*16 + q*4) << 2));
        #pragma unroll
        for (int mi = 0; mi < 4; ++mi) { acc[0][mi] = bA; acc[1][mi] = bB; }
      }
      #pragma unroll
      for (int m = 0; m < 4; ++m) {
        const int r = m*16 + lcol;
        // two passes of 4 frags (caps transient registers at 16)
        #pragma unroll
        for (int kb = 0; kb < 2; ++kb) {
          bf16x8 hf[4];
          #pragma unroll
          for (int kk = 0; kk < 4; ++kk)
            hf[kk] = *(const bf16x8*)(lds + LDS_H1 + r*512 + (((4*(kb*4+kk) + q) ^ lcol) << 4));
          __builtin_amdgcn_s_setprio(1);
          #pragma unroll
          for (int kk = 0; kk < 4; ++kk) {
            acc[0][m] = __builtin_amdgcn_mfma_f32_16x16x32_bf16(w2f[(kb*4+kk)*2+0], hf[kk], acc[0][m], 0,0,0);
            acc[1][m] = __builtin_amdgcn_mfma_f32_16x16x32_bf16(w2f[(kb*4+kk)*2+1], hf[kk], acc[1][m], 0,0,0);
          }
          __builtin_amdgcn_s_setprio(0);
        }
      }
      #pragma unroll
      for (int n = 0; n < 2; ++n) {
        const int nbyte = (wave*2+n)*32 + q*8;
        const int chunk = nbyte >> 4, within = nbyte & 15;
        #pragma unroll
        for (int m = 0; m < 4; ++m) {
          const int r = m*16 + lcol;
          float v0 = fmaxf(acc[n][m][0], 0.f);
          float v1 = fmaxf(acc[n][m][1], 0.f);
          float v2 = fmaxf(acc[n][m][2], 0.f);
          float v3 = fmaxf(acc[n][m][3], 0.f);
          u32x2 t; t.x = cvt_pk_bf16(v0, v1); t.y = cvt_pk_bf16(v2, v3);
          *(u32x2*)(lds + LDS_H2 + r*512 + ((chunk ^ lcol) << 4) + within) = t;
        }
      }
    }
    __syncthreads();  // B2

    // ============ phase 3 (K-split): each wave 2m x 3nt x 4kk; f32 partial exchange
    //              through dead H1 region; kh=1 writes, kh=0 finishes ============
    {
      f32x4 acc3[2][3];   // [mi][j]
      #pragma unroll
      for (int mi = 0; mi < 2; ++mi)
        #pragma unroll
        for (int j = 0; j < 3; ++j) acc3[mi][j] = zero4;
      #pragma unroll
      for (int mi = 0; mi < 2; ++mi) {
        const int r = (mh3*2 + mi)*16 + lcol;
        bf16x8 hf[4];
        #pragma unroll
        for (int kk = 0; kk < 4; ++kk)
          hf[kk] = *(const bf16x8*)(lds + LDS_H2 + r*512 + (((4*(kh*4+kk) + q) ^ lcol) << 4));
        __builtin_amdgcn_s_setprio(1);
        #pragma unroll
        for (int kk = 0; kk < 4; ++kk)
          #pragma unroll
          for (int j = 0; j < 3; ++j)
            acc3[mi][j] = __builtin_amdgcn_mfma_f32_16x16x32_bf16(w3f[kk*3+j], hf[kk], acc3[mi][j], 0,0,0);
        __builtin_amdgcn_s_setprio(0);
      }
      if (kh) {
        #pragma unroll
        for (int mi = 0; mi < 2; ++mi)
          #pragma unroll
          for (int j = 0; j < 3; ++j)
            *(f32x4*)(lds + LDS_H1 + (((sub3*6 + mi*3 + j) << 10) + lane*16)) = acc3[mi][j];
      }
      __syncthreads();  // B3a (partial exchange)
      if (!kh) {
        #pragma unroll
        for (int j = 0; j < 3; ++j) {
          const int nt = np3*3 + j;
          f32x4 bj = *(const f32x4*)(lds + LDS_B3 + ((nt*16 + q*4) << 2));
          #pragma unroll
          for (int mi = 0; mi < 2; ++mi) {
            f32x4 part = *(const f32x4*)(lds + LDS_H1 + (((sub3*6 + mi*3 + j) << 10) + lane*16));
            f32x4 v = acc3[mi][j] + part + bj;
            const int r = (mh3*2 + mi)*16 + lcol;
            if (nt < 4) {
              float4 o;
              o.x = v[0]; o.y = v[1]; o.z = v[2]; o.w = v[3];
              *(float4*)&out[(size_t)(row0 + r)*1024 + p*64 + nt*16 + q*4] = o;
            } else {
              const int kbyte = (nt-4)*32 + q*8;        // carry channels at XC k 0..31
              const int chunk = kbyte >> 4, within = kbyte & 15;
              u32x2 t;
              t.x = cvt_pk_bf16(v[0], v[1]);
              t.y = cvt_pk_bf16(v[2], v[3]);
              *(u32x2*)(lds + LDS_XC + r*128 + ((chunk ^ (r & 7)) << 4) + within) = t;
            }
          }
        }
      }
    }
    __syncthreads();  // B3
  }
}

extern "C" void kernel_launch(void* const* d_in, const int* in_sizes, int n_in,
                              void* d_out, int out_size, void* d_ws, size_t ws_size,
                              hipStream_t stream) {
  const float* bias_a = (const float*)d_in[0];
  const float* bias_b = (const float*)d_in[1];
  const float* op     = (const float*)d_in[2];
  const float* W1     = (const float*)d_in[3];
  const float* b1     = (const float*)d_in[4];
  const float* W2     = (const float*)d_in[5];
  const float* b2     = (const float*)d_in[6];
  const float* W3     = (const float*)d_in[7];
  const float* b3     = (const float*)d_in[8];
  float* out = (float*)d_out;
  unsigned short* wp = (unsigned short*)d_ws;

  hipFuncSetAttribute((const void*)scan_kernel,
                      hipFuncAttributeMaxDynamicSharedMemorySize, LDS_TOTAL);

  pack_weights_kernel<<<544, 256, 0, stream>>>(W1, W2, W3, wp);
  scan_kernel<<<256, 512, LDS_TOTAL, stream>>>(bias_a, bias_b, op, b1, b2, b3, wp, out);
}

// Round 9
// 99.376 us; speedup vs baseline: 1.6438x; 1.1912x over previous
//
#include <hip/hip_runtime.h>

// SlotEquivariantHead: 16-step digit scan; per step MLP 162->256->256->96, 32 carry fed back.
// Round 9 = R8 (K-split P3, W3 frags in regs, biases in LDS) + 24-reg diet to kill R8's
// ~9-reg spill:
//  (1) p+1 global loads issued at loop TOP (tmps live only during P1), consumed post-B1.
//      No cross-position pf registers (-16 in the P2/P3 pressure peak).
//  (2) P1 operand reads split 4+2 (-8 transient in P1).
// 8 waves/block, 64 rows/block, grid 256, 2 waves/SIMD. Weight regs: 48+64+48 = 160.

typedef __attribute__((ext_vector_type(8))) short bf16x8;
typedef __attribute__((ext_vector_type(4))) float f32x4;
typedef __attribute__((ext_vector_type(2))) unsigned int u32x2;
typedef __attribute__((ext_vector_type(4))) unsigned int u32x4;

#define LDS_XAB 0        // 16 KB: [64 r][128 k] bf16, 256B rows, swz chunk^(r&15)
#define LDS_XC  16384    //  8 KB: [64 r][64 k]  bf16, 128B rows, swz chunk^(r&7)
#define LDS_H1  24576    // 32 KB: [64 r][256 n] bf16 (P3 reuses first 24KB as f32 scratch)
#define LDS_H2  57344    // 32 KB
#define LDS_B1  90112    // 1 KB f32 b1
#define LDS_B2  91136    // 1 KB f32 b2
#define LDS_B3  92160    // 384 B f32 b3
#define LDS_TOTAL 92672

__device__ inline unsigned short f32_to_bf16(float f) {
  unsigned int u = __builtin_bit_cast(unsigned int, f);
  u += 0x7FFFu + ((u >> 16) & 1u);
  return (unsigned short)(u >> 16);
}

__device__ inline unsigned int cvt_pk_bf16(float lo, float hi) {
  unsigned int r;
  asm("v_cvt_pk_bf16_f32 %0, %1, %2" : "=v"(r) : "v"(lo), "v"(hi));
  return r;
}

// Pack W1 (rows permuted, K-pad 192), W2 (256x256), W3 (256x96) into bf16 MFMA fragment
// layout: frag(kk,nt): lane l, elem j <- W[kk*32 + (l>>4)*8 + j][nt*16 + (l&15)].
// W1 row permutation k' -> source row: [0,128) a|b direct; [128,160) carry = 130+(k'-128);
// {160,161} op = 128+(k'-160); [162,192) zero.  (matches XC tail = [carry|op|pad])
__global__ void pack_weights_kernel(const float* __restrict__ W1,
                                    const float* __restrict__ W2,
                                    const float* __restrict__ W3,
                                    unsigned short* __restrict__ wp) {
  int idx = blockIdx.x * 256 + threadIdx.x;
  if (idx >= 139264) return;
  int j, lane, frag, nt, kk, k, n;
  float v = 0.0f;
  if (idx < 49152) {
    int e = idx;
    j = e & 7; lane = (e >> 3) & 63; frag = e >> 9;
    nt = frag % 16; kk = frag / 16;
    k = kk * 32 + ((lane >> 4) << 3) + j;
    n = nt * 16 + (lane & 15);
    int ksrc;
    if (k < 128)      ksrc = k;
    else if (k < 160) ksrc = 130 + (k - 128);   // carry rows
    else if (k < 162) ksrc = 128 + (k - 160);   // op rows
    else              ksrc = -1;                 // zero pad
    v = (ksrc >= 0) ? W1[ksrc * 256 + n] : 0.0f;
  } else if (idx < 114688) {
    int e = idx - 49152;
    j = e & 7; lane = (e >> 3) & 63; frag = e >> 9;
    nt = frag % 16; kk = frag / 16;
    k = kk * 32 + ((lane >> 4) << 3) + j;
    n = nt * 16 + (lane & 15);
    v = W2[k * 256 + n];
  } else {
    int e = idx - 114688;
    j = e & 7; lane = (e >> 3) & 63; frag = e >> 9;
    nt = frag % 6; kk = frag / 6;
    k = kk * 32 + ((lane >> 4) << 3) + j;
    n = nt * 16 + (lane & 15);
    v = W3[k * 96 + n];
  }
  wp[idx] = f32_to_bf16(v);
}

__global__ __launch_bounds__(512, 2) void scan_kernel(
    const float* __restrict__ Ain, const float* __restrict__ Bin,
    const float* __restrict__ Op,
    const float* __restrict__ b1, const float* __restrict__ b2,
    const float* __restrict__ b3,
    const unsigned short* __restrict__ wp,
    float* __restrict__ out) {
  extern __shared__ char lds[];

  const int tid  = threadIdx.x;
  const int wave = tid >> 6, lane = tid & 63;
  const int lcol = lane & 15;      // batch-row within tile
  const int q    = lane >> 4;      // k-quad for reads; n-quad for writes
  const int row0 = blockIdx.x * 64;
  // P3 K-split roles: kh = K-half, sub3 -> (m-pair mh3, nt-triple np3)
  const int kh   = wave & 1;
  const int sub3 = wave >> 1;
  const int mh3  = sub3 >> 1, np3 = sub3 & 1;

  // ---- persistent weight fragments:
  //  P1/P2: wave owns nt = wave*2 + n (n = 0,1)
  //  P3:    wave owns kk in [4kh,4kh+4) x nt in [3np3, 3np3+3): 12 frags
  bf16x8 w1f[12], w2f[16], w3f[12];
  {
    const char* wb = (const char*)wp;
    #pragma unroll
    for (int kk = 0; kk < 6; ++kk)
      #pragma unroll
      for (int n = 0; n < 2; ++n)
        w1f[kk*2+n] = *(const bf16x8*)(wb + (size_t)(kk*16 + wave*2 + n)*1024 + lane*16);
    const char* wb2 = wb + 98304;
    #pragma unroll
    for (int kk = 0; kk < 8; ++kk)
      #pragma unroll
      for (int n = 0; n < 2; ++n)
        w2f[kk*2+n] = *(const bf16x8*)(wb2 + (size_t)(kk*16 + wave*2 + n)*1024 + lane*16);
    const char* wb3 = wb + 229376;
    #pragma unroll
    for (int kk = 0; kk < 4; ++kk)
      #pragma unroll
      for (int j = 0; j < 3; ++j)
        w3f[kk*3+j] = *(const bf16x8*)(wb3 + (size_t)((kh*4+kk)*6 + np3*3 + j)*1024 + lane*16);
  }

  // ---- biases -> LDS (f32, broadcast-read at acc init / P3 finish)
  if (tid < 256) ((float*)(lds + LDS_B1))[tid] = b1[tid];
  else           ((float*)(lds + LDS_B2))[tid - 256] = b2[tid - 256];
  if (tid < 96)  ((float*)(lds + LDS_B3))[tid] = b3[tid];

  // ---- XC init: k 0..31 carry=0, 32..33 op, 34..63 zero
  for (int i = tid; i < 4096; i += 512) {
    int r = i >> 6, kx = i & 63;
    unsigned short v = 0;
    if (kx == 32 || kx == 33) v = f32_to_bf16(Op[(size_t)(row0 + r)*2 + (kx - 32)]);
    int chunk = kx >> 3, within = (kx & 7) * 2;
    *(unsigned short*)(lds + LDS_XC + r*128 + ((chunk ^ (r & 7)) << 4) + within) = v;
  }

  // ---- a/b staging geometry: thread covers row srow, 16 floats at part*16 of [a|b] row
  const int part = tid & 7;
  const int srow = tid >> 3;
  const float* srcp = (part < 4 ? Ain : Bin) + (size_t)(row0 + srow)*1024 + (part & 3)*16;

  {  // p=0 synchronous stage
    float4 pv[4];
    #pragma unroll
    for (int jj = 0; jj < 4; ++jj) pv[jj] = *(const float4*)(srcp + jj*4);
    unsigned int u[8];
    #pragma unroll
    for (int jj = 0; jj < 4; ++jj) {
      u[jj*2]   = cvt_pk_bf16(pv[jj].x, pv[jj].y);
      u[jj*2+1] = cvt_pk_bf16(pv[jj].z, pv[jj].w);
    }
    u32x4 t0 = {u[0],u[1],u[2],u[3]}, t1 = {u[4],u[5],u[6],u[7]};
    *(u32x4*)(lds + LDS_XAB + srow*256 + (((part*2)   ^ (srow & 15)) << 4)) = t0;
    *(u32x4*)(lds + LDS_XAB + srow*256 + (((part*2+1) ^ (srow & 15)) << 4)) = t1;
  }
  __syncthreads();

  const f32x4 zero4 = {0.f, 0.f, 0.f, 0.f};

  #pragma unroll 1
  for (int p = 0; p < 16; ++p) {
    // ---- issue p+1 a/b loads NOW; results consumed after B1 (latency hides under P1)
    float4 tmp0, tmp1, tmp2, tmp3;
    if (p < 15) {
      const float* s1 = srcp + (p+1)*64;
      tmp0 = *(const float4*)(s1 + 0);
      tmp1 = *(const float4*)(s1 + 4);
      tmp2 = *(const float4*)(s1 + 8);
      tmp3 = *(const float4*)(s1 + 12);
    }

    // ============ phase 1: Y^T = W1^T @ X^T -> relu -> H1 [64r][256n] ============
    {
      f32x4 acc[2][4];
      {
        f32x4 bA = *(const f32x4*)(lds + LDS_B1 + (((wave*2+0)*16 + q*4) << 2));
        f32x4 bB = *(const f32x4*)(lds + LDS_B1 + (((wave*2+1)*16 + q*4) << 2));
        #pragma unroll
        for (int mi = 0; mi < 4; ++mi) { acc[0][mi] = bA; acc[1][mi] = bB; }
      }
      #pragma unroll
      for (int m = 0; m < 4; ++m) {
        const int r = m*16 + lcol;
        {
          bf16x8 xf[4];
          #pragma unroll
          for (int kk = 0; kk < 4; ++kk)
            xf[kk] = *(const bf16x8*)(lds + LDS_XAB + r*256 + (((4*kk + q) ^ lcol) << 4));
          __builtin_amdgcn_s_setprio(1);
          #pragma unroll
          for (int kk = 0; kk < 4; ++kk) {
            acc[0][m] = __builtin_amdgcn_mfma_f32_16x16x32_bf16(w1f[kk*2+0], xf[kk], acc[0][m], 0,0,0);
            acc[1][m] = __builtin_amdgcn_mfma_f32_16x16x32_bf16(w1f[kk*2+1], xf[kk], acc[1][m], 0,0,0);
          }
          __builtin_amdgcn_s_setprio(0);
        }
        {
          bf16x8 xc[2];
          #pragma unroll
          for (int kk = 0; kk < 2; ++kk)
            xc[kk] = *(const bf16x8*)(lds + LDS_XC + r*128 + (((4*kk + q) ^ (lcol & 7)) << 4));
          __builtin_amdgcn_s_setprio(1);
          #pragma unroll
          for (int kk = 0; kk < 2; ++kk) {
            acc[0][m] = __builtin_amdgcn_mfma_f32_16x16x32_bf16(w1f[(4+kk)*2+0], xc[kk], acc[0][m], 0,0,0);
            acc[1][m] = __builtin_amdgcn_mfma_f32_16x16x32_bf16(w1f[(4+kk)*2+1], xc[kk], acc[1][m], 0,0,0);
          }
          __builtin_amdgcn_s_setprio(0);
        }
      }
      #pragma unroll
      for (int n = 0; n < 2; ++n) {
        const int nbyte = (wave*2+n)*32 + q*8;
        const int chunk = nbyte >> 4, within = nbyte & 15;
        #pragma unroll
        for (int m = 0; m < 4; ++m) {
          const int r = m*16 + lcol;
          float v0 = fmaxf(acc[n][m][0], 0.f);
          float v1 = fmaxf(acc[n][m][1], 0.f);
          float v2 = fmaxf(acc[n][m][2], 0.f);
          float v3 = fmaxf(acc[n][m][3], 0.f);
          u32x2 t; t.x = cvt_pk_bf16(v0, v1); t.y = cvt_pk_bf16(v2, v3);
          *(u32x2*)(lds + LDS_H1 + r*512 + ((chunk ^ lcol) << 4) + within) = t;
        }
      }
    }
    __syncthreads();  // B1

    // ---- stage XAB(p+1) from tmps (loads issued at loop top; B1 drained vmcnt) ----
    if (p < 15) {
      unsigned int u[8];
      u[0] = cvt_pk_bf16(tmp0.x, tmp0.y);  u[1] = cvt_pk_bf16(tmp0.z, tmp0.w);
      u[2] = cvt_pk_bf16(tmp1.x, tmp1.y);  u[3] = cvt_pk_bf16(tmp1.z, tmp1.w);
      u[4] = cvt_pk_bf16(tmp2.x, tmp2.y);  u[5] = cvt_pk_bf16(tmp2.z, tmp2.w);
      u[6] = cvt_pk_bf16(tmp3.x, tmp3.y);  u[7] = cvt_pk_bf16(tmp3.z, tmp3.w);
      u32x4 t0 = {u[0],u[1],u[2],u[3]}, t1 = {u[4],u[5],u[6],u[7]};
      *(u32x4*)(lds + LDS_XAB + srow*256 + (((part*2)   ^ (srow & 15)) << 4)) = t0;
      *(u32x4*)(lds + LDS_XAB + srow*256 + (((part*2+1) ^ (srow & 15)) << 4)) = t1;
    }

    // ============ phase 2: W2^T @ H1^T -> relu -> H2 ============
    {
      f32x4 acc[2][4];
      {
        f32x4 bA = *(const f32x4*)(lds + LDS_B2 + (((wave*2+0)*16 + q*4) << 2));
        f32x4 bB = *(const f32x4*)(lds + LDS_B2 + (((wave*2+1)*16 + q*4) << 2));
        #pragma unroll
        for (int mi = 0; mi < 4; ++mi) { acc[0][mi] = bA; acc[1][mi] = bB; }
      }
      #pragma unroll
      for (int m = 0; m < 4; ++m) {
        const int r = m*16 + lcol;
        // two passes of 4 frags (caps transient registers at 16)
        #pragma unroll
        for (int kb = 0; kb < 2; ++kb) {
          bf16x8 hf[4];
          #pragma unroll
          for (int kk = 0; kk < 4; ++kk)
            hf[kk] = *(const bf16x8*)(lds + LDS_H1 + r*512 + (((4*(kb*4+kk) + q) ^ lcol) << 4));
          __builtin_amdgcn_s_setprio(1);
          #pragma unroll
          for (int kk = 0; kk < 4; ++kk) {
            acc[0][m] = __builtin_amdgcn_mfma_f32_16x16x32_bf16(w2f[(kb*4+kk)*2+0], hf[kk], acc[0][m], 0,0,0);
            acc[1][m] = __builtin_amdgcn_mfma_f32_16x16x32_bf16(w2f[(kb*4+kk)*2+1], hf[kk], acc[1][m], 0,0,0);
          }
          __builtin_amdgcn_s_setprio(0);
        }
      }
      #pragma unroll
      for (int n = 0; n < 2; ++n) {
        const int nbyte = (wave*2+n)*32 + q*8;
        const int chunk = nbyte >> 4, within = nbyte & 15;
        #pragma unroll
        for (int m = 0; m < 4; ++m) {
          const int r = m*16 + lcol;
          float v0 = fmaxf(acc[n][m][0], 0.f);
          float v1 = fmaxf(acc[n][m][1], 0.f);
          float v2 = fmaxf(acc[n][m][2], 0.f);
          float v3 = fmaxf(acc[n][m][3], 0.f);
          u32x2 t; t.x = cvt_pk_bf16(v0, v1); t.y = cvt_pk_bf16(v2, v3);
          *(u32x2*)(lds + LDS_H2 + r*512 + ((chunk ^ lcol) << 4) + within) = t;
        }
      }
    }
    __syncthreads();  // B2

    // ============ phase 3 (K-split): each wave 2m x 3nt x 4kk; f32 partial exchange
    //              through dead H1 region; kh=1 writes, kh=0 finishes ============
    {
      f32x4 acc3[2][3];   // [mi][j]
      #pragma unroll
      for (int mi = 0; mi < 2; ++mi)
        #pragma unroll
        for (int j = 0; j < 3; ++j) acc3[mi][j] = zero4;
      #pragma unroll
      for (int mi = 0; mi < 2; ++mi) {
        const int r = (mh3*2 + mi)*16 + lcol;
        bf16x8 hf[4];
        #pragma unroll
        for (int kk = 0; kk < 4; ++kk)
          hf[kk] = *(const bf16x8*)(lds + LDS_H2 + r*512 + (((4*(kh*4+kk) + q) ^ lcol) << 4));
        __builtin_amdgcn_s_setprio(1);
        #pragma unroll
        for (int kk = 0; kk < 4; ++kk)
          #pragma unroll
          for (int j = 0; j < 3; ++j)
            acc3[mi][j] = __builtin_amdgcn_mfma_f32_16x16x32_bf16(w3f[kk*3+j], hf[kk], acc3[mi][j], 0,0,0);
        __builtin_amdgcn_s_setprio(0);
      }
      if (kh) {
        #pragma unroll
        for (int mi = 0; mi < 2; ++mi)
          #pragma unroll
          for (int j = 0; j < 3; ++j)
            *(f32x4*)(lds + LDS_H1 + (((sub3*6 + mi*3 + j) << 10) + lane*16)) = acc3[mi][j];
      }
      __syncthreads();  // B3a (partial exchange)
      if (!kh) {
        #pragma unroll
        for (int j = 0; j < 3; ++j) {
          const int nt = np3*3 + j;
          f32x4 bj = *(const f32x4*)(lds + LDS_B3 + ((nt*16 + q*4) << 2));
          #pragma unroll
          for (int mi = 0; mi < 2; ++mi) {
            f32x4 part = *(const f32x4*)(lds + LDS_H1 + (((sub3*6 + mi*3 + j) << 10) + lane*16));
            f32x4 v = acc3[mi][j] + part + bj;
            const int r = (mh3*2 + mi)*16 + lcol;
            if (nt < 4) {
              float4 o;
              o.x = v[0]; o.y = v[1]; o.z = v[2]; o.w = v[3];
              *(float4*)&out[(size_t)(row0 + r)*1024 + p*64 + nt*16 + q*4] = o;
            } else {
              const int kbyte = (nt-4)*32 + q*8;        // carry channels at XC k 0..31
              const int chunk = kbyte >> 4, within = kbyte & 15;
              u32x2 t;
              t.x = cvt_pk_bf16(v[0], v[1]);
              t.y = cvt_pk_bf16(v[2], v[3]);
              *(u32x2*)(lds + LDS_XC + r*128 + ((chunk ^ (r & 7)) << 4) + within) = t;
            }
          }
        }
      }
    }
    __syncthreads();  // B3
  }
}

extern "C" void kernel_launch(void* const* d_in, const int* in_sizes, int n_in,
                              void* d_out, int out_size, void* d_ws, size_t ws_size,
                              hipStream_t stream) {
  const float* bias_a = (const float*)d_in[0];
  const float* bias_b = (const float*)d_in[1];
  const float* op     = (const float*)d_in[2];
  const float* W1     = (const float*)d_in[3];
  const float* b1     = (const float*)d_in[4];
  const float* W2     = (const float*)d_in[5];
  const float* b2     = (const float*)d_in[6];
  const float* W3     = (const float*)d_in[7];
  const float* b3     = (const float*)d_in[8];
  float* out = (float*)d_out;
  unsigned short* wp = (unsigned short*)d_ws;

  hipFuncSetAttribute((const void*)scan_kernel,
                      hipFuncAttributeMaxDynamicSharedMemorySize, LDS_TOTAL);

  pack_weights_kernel<<<544, 256, 0, stream>>>(W1, W2, W3, wp);
  scan_kernel<<<256, 512, LDS_TOTAL, stream>>>(bias_a, bias_b, op, b1, b2, b3, wp, out);
}

// Round 10
// 88.193 us; speedup vs baseline: 1.8522x; 1.1268x over previous
//
#include <hip/hip_runtime.h>

// SlotEquivariantHead: 16-step digit scan; per step MLP 162->256->256->96, 32 carry fed back.
// Round 10 = R4 base (93us, zero spill: swapped-operand MFMA, W1/W2 frags in regs, W3 in LDS)
// restructured into a cross-position software pipeline that overlaps the two INDEPENDENT
// dependency chains:
//   Phase A: P3(p-1) [H2->y,carry; W3 from LDS]  INTERLEAVED with  P1a(p) [a|b channels only]
//   Phase B: P1b(p)  [carry+op channels]  -> H1
//   Phase C: P2(p) -> H2, + stage XAB(p+1) (loads issued before P2, consumed after)
// The scan's serial dependency is only through the carry (2/6 of P1's K) -> P1a is legal in A.
// Biases in LDS (frees 28 regs). 8 waves/block, 64 rows/block, grid 256, 2 waves/SIMD.

typedef __attribute__((ext_vector_type(8))) short bf16x8;
typedef __attribute__((ext_vector_type(4))) float f32x4;
typedef __attribute__((ext_vector_type(2))) unsigned int u32x2;
typedef __attribute__((ext_vector_type(4))) unsigned int u32x4;

#define LDS_XAB 0        // 16 KB: [64 r][128 k] bf16, 256B rows, swz chunk^(r&15)
#define LDS_XC  16384    //  8 KB: [64 r][64 k]  bf16, 128B rows, swz chunk^(r&7)
#define LDS_H1  24576    // 32 KB: [64 r][256 n] bf16, 512B rows, swz chunk^(r&15)
#define LDS_H2  57344    // 32 KB
#define LDS_W3  90112    // 48 KB packed W3 fragments (frag-linear)
#define LDS_B1  139264   // 1 KB f32 b1
#define LDS_B2  140288   // 1 KB f32 b2
#define LDS_B3  141312   // 384 B f32 b3
#define LDS_TOTAL 141696

#define MFMA16(wf_, xf_, c_) c_ = __builtin_amdgcn_mfma_f32_16x16x32_bf16(wf_, xf_, c_, 0,0,0)

__device__ inline unsigned short f32_to_bf16(float f) {
  unsigned int u = __builtin_bit_cast(unsigned int, f);
  u += 0x7FFFu + ((u >> 16) & 1u);
  return (unsigned short)(u >> 16);
}

__device__ inline unsigned int cvt_pk_bf16(float lo, float hi) {
  unsigned int r;
  asm("v_cvt_pk_bf16_f32 %0, %1, %2" : "=v"(r) : "v"(lo), "v"(hi));
  return r;
}

// Pack W1 (rows permuted, K-pad 192), W2 (256x256), W3 (256x96) into bf16 MFMA fragment
// layout: frag(kk,nt): lane l, elem j <- W[kk*32 + (l>>4)*8 + j][nt*16 + (l&15)].
// W1 row permutation k' -> source row: [0,128) a|b direct; [128,160) carry = 130+(k'-128);
// {160,161} op = 128+(k'-160); [162,192) zero.  (matches XC tail = [carry|op|pad])
__global__ void pack_weights_kernel(const float* __restrict__ W1,
                                    const float* __restrict__ W2,
                                    const float* __restrict__ W3,
                                    unsigned short* __restrict__ wp) {
  int idx = blockIdx.x * 256 + threadIdx.x;
  if (idx >= 139264) return;
  int j, lane, frag, nt, kk, k, n;
  float v = 0.0f;
  if (idx < 49152) {
    int e = idx;
    j = e & 7; lane = (e >> 3) & 63; frag = e >> 9;
    nt = frag % 16; kk = frag / 16;
    k = kk * 32 + ((lane >> 4) << 3) + j;
    n = nt * 16 + (lane & 15);
    int ksrc;
    if (k < 128)      ksrc = k;
    else if (k < 160) ksrc = 130 + (k - 128);   // carry rows
    else if (k < 162) ksrc = 128 + (k - 160);   // op rows
    else              ksrc = -1;                 // zero pad
    v = (ksrc >= 0) ? W1[ksrc * 256 + n] : 0.0f;
  } else if (idx < 114688) {
    int e = idx - 49152;
    j = e & 7; lane = (e >> 3) & 63; frag = e >> 9;
    nt = frag % 16; kk = frag / 16;
    k = kk * 32 + ((lane >> 4) << 3) + j;
    n = nt * 16 + (lane & 15);
    v = W2[k * 256 + n];
  } else {
    int e = idx - 114688;
    j = e & 7; lane = (e >> 3) & 63; frag = e >> 9;
    nt = frag % 6; kk = frag / 6;
    k = kk * 32 + ((lane >> 4) << 3) + j;
    n = nt * 16 + (lane & 15);
    v = W3[k * 96 + n];
  }
  wp[idx] = f32_to_bf16(v);
}

__global__ __launch_bounds__(512, 2) void scan_kernel(
    const float* __restrict__ Ain, const float* __restrict__ Bin,
    const float* __restrict__ Op,
    const float* __restrict__ b1, const float* __restrict__ b2,
    const float* __restrict__ b3,
    const unsigned short* __restrict__ wp,
    float* __restrict__ out) {
  extern __shared__ char lds[];

  const int tid  = threadIdx.x;
  const int wave = tid >> 6, lane = tid & 63;
  const int lcol = lane & 15;      // batch-row within tile
  const int q    = lane >> 4;      // k-quad for reads; n-quad for writes
  const int row0 = blockIdx.x * 64;
  const int mw = wave >> 1, ngg = wave & 1;   // P3 roles (R4)

  // ---- persistent weight fragments: P1/P2 wave owns nt = wave*2 + n (n = 0,1)
  bf16x8 w1f[12], w2f[16];
  {
    const char* wb = (const char*)wp;
    #pragma unroll
    for (int kk = 0; kk < 6; ++kk)
      #pragma unroll
      for (int n = 0; n < 2; ++n)
        w1f[kk*2+n] = *(const bf16x8*)(wb + (size_t)(kk*16 + wave*2 + n)*1024 + lane*16);
    const char* wb2 = wb + 98304;
    #pragma unroll
    for (int kk = 0; kk < 8; ++kk)
      #pragma unroll
      for (int n = 0; n < 2; ++n)
        w2f[kk*2+n] = *(const bf16x8*)(wb2 + (size_t)(kk*16 + wave*2 + n)*1024 + lane*16);
  }

  // ---- biases -> LDS (f32 broadcast reads at acc init)
  if (tid < 256) ((float*)(lds + LDS_B1))[tid] = b1[tid];
  else           ((float*)(lds + LDS_B2))[tid - 256] = b2[tid - 256];
  if (tid < 96)  ((float*)(lds + LDS_B3))[tid] = b3[tid];

  // ---- W3 fragments -> LDS (one-time, frag-linear => lane-linear conflict-free reads)
  {
    const char* w3src = (const char*)wp + 229376;
    #pragma unroll
    for (int i = 0; i < 6; ++i)
      *(u32x4*)(lds + LDS_W3 + (size_t)(tid + i*512)*16) =
          *(const u32x4*)(w3src + (size_t)(tid + i*512)*16);
  }
  // ---- XC init: k 0..31 carry=0, 32..33 op, 34..63 zero
  for (int i = tid; i < 4096; i += 512) {
    int r = i >> 6, kx = i & 63;
    unsigned short v = 0;
    if (kx == 32 || kx == 33) v = f32_to_bf16(Op[(size_t)(row0 + r)*2 + (kx - 32)]);
    int chunk = kx >> 3, within = (kx & 7) * 2;
    *(unsigned short*)(lds + LDS_XC + r*128 + ((chunk ^ (r & 7)) << 4) + within) = v;
  }

  // ---- a/b staging geometry: thread covers row srow, 16 floats at part*16 of [a|b] row
  const int part = tid & 7;
  const int srow = tid >> 3;
  const float* srcp = (part < 4 ? Ain : Bin) + (size_t)(row0 + srow)*1024 + (part & 3)*16;

  {  // p=0 synchronous stage
    float4 pv[4];
    #pragma unroll
    for (int jj = 0; jj < 4; ++jj) pv[jj] = *(const float4*)(srcp + jj*4);
    unsigned int u[8];
    #pragma unroll
    for (int jj = 0; jj < 4; ++jj) {
      u[jj*2]   = cvt_pk_bf16(pv[jj].x, pv[jj].y);
      u[jj*2+1] = cvt_pk_bf16(pv[jj].z, pv[jj].w);
    }
    u32x4 t0 = {u[0],u[1],u[2],u[3]}, t1 = {u[4],u[5],u[6],u[7]};
    *(u32x4*)(lds + LDS_XAB + srow*256 + (((part*2)   ^ (srow & 15)) << 4)) = t0;
    *(u32x4*)(lds + LDS_XAB + srow*256 + (((part*2+1) ^ (srow & 15)) << 4)) = t1;
  }
  __syncthreads();

  const int r3 = mw*16 + lcol;   // P3 batch-row

  #pragma unroll 1
  for (int p = 0; p < 16; ++p) {
    // ================= phase A: P3(p-1) interleaved with P1a(p) =================
    f32x4 acc[2][4];   // P1 accumulators (persist A -> B)
    {
      f32x4 bA = *(const f32x4*)(lds + LDS_B1 + (((wave*2+0)*16 + q*4) << 2));
      f32x4 bB = *(const f32x4*)(lds + LDS_B1 + (((wave*2+1)*16 + q*4) << 2));
      #pragma unroll
      for (int mi = 0; mi < 4; ++mi) { acc[0][mi] = bA; acc[1][mi] = bB; }
    }
    if (p == 0) {
      #pragma unroll
      for (int m = 0; m < 4; ++m) {
        const int r = m*16 + lcol;
        bf16x8 xf[4];
        #pragma unroll
        for (int kk = 0; kk < 4; ++kk)
          xf[kk] = *(const bf16x8*)(lds + LDS_XAB + r*256 + (((4*kk + q) ^ lcol) << 4));
        __builtin_amdgcn_s_setprio(1);
        #pragma unroll
        for (int kk = 0; kk < 4; ++kk) {
          MFMA16(w1f[kk*2+0], xf[kk], acc[0][m]);
          MFMA16(w1f[kk*2+1], xf[kk], acc[1][m]);
        }
        __builtin_amdgcn_s_setprio(0);
      }
    } else {
      f32x4 acc3[3];
      #pragma unroll
      for (int j = 0; j < 3; ++j)
        acc3[j] = *(const f32x4*)(lds + LDS_B3 + ((((ngg*3+j)*16) + q*4) << 2));
      #pragma unroll
      for (int s = 0; s < 4; ++s) {
        const int r = s*16 + lcol;
        // P1a reads (issued first -> P1a MFMAs start while P3 reads in flight)
        bf16x8 xf[4];
        #pragma unroll
        for (int kk = 0; kk < 4; ++kk)
          xf[kk] = *(const bf16x8*)(lds + LDS_XAB + r*256 + (((4*kk + q) ^ lcol) << 4));
        // P3 chunk reads: kk = 2s, 2s+1
        bf16x8 hfa = *(const bf16x8*)(lds + LDS_H2 + r3*512 + (((4*(2*s)   + q) ^ lcol) << 4));
        bf16x8 hfb = *(const bf16x8*)(lds + LDS_H2 + r3*512 + (((4*(2*s+1) + q) ^ lcol) << 4));
        bf16x8 wfa[3], wfb[3];
        #pragma unroll
        for (int j = 0; j < 3; ++j) {
          wfa[j] = *(const bf16x8*)(lds + LDS_W3 + (size_t)((2*s)*6   + ngg*3 + j)*1024 + lane*16);
          wfb[j] = *(const bf16x8*)(lds + LDS_W3 + (size_t)((2*s+1)*6 + ngg*3 + j)*1024 + lane*16);
        }
        __builtin_amdgcn_s_setprio(1);
        #pragma unroll
        for (int kk = 0; kk < 4; ++kk) {
          MFMA16(w1f[kk*2+0], xf[kk], acc[0][s]);
          MFMA16(w1f[kk*2+1], xf[kk], acc[1][s]);
        }
        #pragma unroll
        for (int j = 0; j < 3; ++j) MFMA16(wfa[j], hfa, acc3[j]);
        #pragma unroll
        for (int j = 0; j < 3; ++j) MFMA16(wfb[j], hfb, acc3[j]);
        __builtin_amdgcn_s_setprio(0);
      }
      // P3 epilogue (position p-1)
      #pragma unroll
      for (int j = 0; j < 3; ++j) {
        const int nt = ngg*3 + j;
        if (nt < 4) {
          float4 o;
          o.x = acc3[j][0]; o.y = acc3[j][1]; o.z = acc3[j][2]; o.w = acc3[j][3];
          *(float4*)&out[(size_t)(row0 + r3)*1024 + (p-1)*64 + nt*16 + q*4] = o;
        } else {
          const int kbyte = (nt-4)*32 + q*8;            // carry channels at XC k 0..31
          const int chunk = kbyte >> 4, within = kbyte & 15;
          u32x2 t;
          t.x = cvt_pk_bf16(acc3[j][0], acc3[j][1]);
          t.y = cvt_pk_bf16(acc3[j][2], acc3[j][3]);
          *(u32x2*)(lds + LDS_XC + r3*128 + ((chunk ^ (r3 & 7)) << 4) + within) = t;
        }
      }
    }
    __syncthreads();  // A|B (carry visible)

    // ================= phase B: P1b (carry+op K-block) -> relu -> H1 =================
    {
      #pragma unroll
      for (int m = 0; m < 4; ++m) {
        const int r = m*16 + lcol;
        bf16x8 xc[2];
        #pragma unroll
        for (int kk = 0; kk < 2; ++kk)
          xc[kk] = *(const bf16x8*)(lds + LDS_XC + r*128 + (((4*kk + q) ^ (lcol & 7)) << 4));
        __builtin_amdgcn_s_setprio(1);
        MFMA16(w1f[8],  xc[0], acc[0][m]);
        MFMA16(w1f[9],  xc[0], acc[1][m]);
        MFMA16(w1f[10], xc[1], acc[0][m]);
        MFMA16(w1f[11], xc[1], acc[1][m]);
        __builtin_amdgcn_s_setprio(0);
      }
      #pragma unroll
      for (int n = 0; n < 2; ++n) {
        const int nbyte = (wave*2+n)*32 + q*8;
        const int chunk = nbyte >> 4, within = nbyte & 15;
        #pragma unroll
        for (int m = 0; m < 4; ++m) {
          const int r = m*16 + lcol;
          float v0 = fmaxf(acc[n][m][0], 0.f);
          float v1 = fmaxf(acc[n][m][1], 0.f);
          float v2 = fmaxf(acc[n][m][2], 0.f);
          float v3 = fmaxf(acc[n][m][3], 0.f);
          u32x2 t; t.x = cvt_pk_bf16(v0, v1); t.y = cvt_pk_bf16(v2, v3);
          *(u32x2*)(lds + LDS_H1 + r*512 + ((chunk ^ lcol) << 4) + within) = t;
        }
      }
    }
    __syncthreads();  // B|C

    // ================= phase C: P2 -> H2, + stage XAB(p+1) =================
    {
      float4 t0, t1, t2, t3;
      if (p < 15) {   // issue loads early; HBM latency hides under P2
        const float* s1 = srcp + (p+1)*64;
        t0 = *(const float4*)(s1 + 0);
        t1 = *(const float4*)(s1 + 4);
        t2 = *(const float4*)(s1 + 8);
        t3 = *(const float4*)(s1 + 12);
      }
      f32x4 acc2[2][4];
      {
        f32x4 bA = *(const f32x4*)(lds + LDS_B2 + (((wave*2+0)*16 + q*4) << 2));
        f32x4 bB = *(const f32x4*)(lds + LDS_B2 + (((wave*2+1)*16 + q*4) << 2));
        #pragma unroll
        for (int mi = 0; mi < 4; ++mi) { acc2[0][mi] = bA; acc2[1][mi] = bB; }
      }
      #pragma unroll
      for (int m = 0; m < 4; ++m) {
        const int r = m*16 + lcol;
        bf16x8 hf[8];
        #pragma unroll
        for (int kk = 0; kk < 8; ++kk)
          hf[kk] = *(const bf16x8*)(lds + LDS_H1 + r*512 + (((4*kk + q) ^ lcol) << 4));
        __builtin_amdgcn_s_setprio(1);
        #pragma unroll
        for (int kk = 0; kk < 8; ++kk) {
          MFMA16(w2f[kk*2+0], hf[kk], acc2[0][m]);
          MFMA16(w2f[kk*2+1], hf[kk], acc2[1][m]);
        }
        __builtin_amdgcn_s_setprio(0);
      }
      #pragma unroll
      for (int n = 0; n < 2; ++n) {
        const int nbyte = (wave*2+n)*32 + q*8;
        const int chunk = nbyte >> 4, within = nbyte & 15;
        #pragma unroll
        for (int m = 0; m < 4; ++m) {
          const int r = m*16 + lcol;
          float v0 = fmaxf(acc2[n][m][0], 0.f);
          float v1 = fmaxf(acc2[n][m][1], 0.f);
          float v2 = fmaxf(acc2[n][m][2], 0.f);
          float v3 = fmaxf(acc2[n][m][3], 0.f);
          u32x2 t; t.x = cvt_pk_bf16(v0, v1); t.y = cvt_pk_bf16(v2, v3);
          *(u32x2*)(lds + LDS_H2 + r*512 + ((chunk ^ lcol) << 4) + within) = t;
        }
      }
      if (p < 15) {   // consume staged loads -> XAB(p+1)
        unsigned int u[8];
        u[0] = cvt_pk_bf16(t0.x, t0.y);  u[1] = cvt_pk_bf16(t0.z, t0.w);
        u[2] = cvt_pk_bf16(t1.x, t1.y);  u[3] = cvt_pk_bf16(t1.z, t1.w);
        u[4] = cvt_pk_bf16(t2.x, t2.y);  u[5] = cvt_pk_bf16(t2.z, t2.w);
        u[6] = cvt_pk_bf16(t3.x, t3.y);  u[7] = cvt_pk_bf16(t3.z, t3.w);
        u32x4 w0 = {u[0],u[1],u[2],u[3]}, w1 = {u[4],u[5],u[6],u[7]};
        *(u32x4*)(lds + LDS_XAB + srow*256 + (((part*2)   ^ (srow & 15)) << 4)) = w0;
        *(u32x4*)(lds + LDS_XAB + srow*256 + (((part*2+1) ^ (srow & 15)) << 4)) = w1;
      }
    }
    __syncthreads();  // C|A
  }

  // ================= final P3(15): H2(15) -> out (no carry needed) =================
  {
    f32x4 acc3[3];
    #pragma unroll
    for (int j = 0; j < 3; ++j)
      acc3[j] = *(const f32x4*)(lds + LDS_B3 + ((((ngg*3+j)*16) + q*4) << 2));
    #pragma unroll
    for (int kk = 0; kk < 8; ++kk) {
      bf16x8 hf = *(const bf16x8*)(lds + LDS_H2 + r3*512 + (((4*kk + q) ^ lcol) << 4));
      #pragma unroll
      for (int j = 0; j < 3; ++j) {
        bf16x8 wf = *(const bf16x8*)(lds + LDS_W3 + (size_t)(kk*6 + ngg*3 + j)*1024 + lane*16);
        MFMA16(wf, hf, acc3[j]);
      }
    }
    #pragma unroll
    for (int j = 0; j < 3; ++j) {
      const int nt = ngg*3 + j;
      if (nt < 4) {
        float4 o;
        o.x = acc3[j][0]; o.y = acc3[j][1]; o.z = acc3[j][2]; o.w = acc3[j][3];
        *(float4*)&out[(size_t)(row0 + r3)*1024 + 15*64 + nt*16 + q*4] = o;
      }
    }
  }
}

extern "C" void kernel_launch(void* const* d_in, const int* in_sizes, int n_in,
                              void* d_out, int out_size, void* d_ws, size_t ws_size,
                              hipStream_t stream) {
  const float* bias_a = (const float*)d_in[0];
  const float* bias_b = (const float*)d_in[1];
  const float* op     = (const float*)d_in[2];
  const float* W1     = (const float*)d_in[3];
  const float* b1     = (const float*)d_in[4];
  const float* W2     = (const float*)d_in[5];
  const float* b2     = (const float*)d_in[6];
  const float* W3     = (const float*)d_in[7];
  const float* b3     = (const float*)d_in[8];
  float* out = (float*)d_out;
  unsigned short* wp = (unsigned short*)d_ws;

  hipFuncSetAttribute((const void*)scan_kernel,
                      hipFuncAttributeMaxDynamicSharedMemorySize, LDS_TOTAL);

  pack_weights_kernel<<<544, 256, 0, stream>>>(W1, W2, W3, wp);
  scan_kernel<<<256, 512, LDS_TOTAL, stream>>>(bias_a, bias_b, op, b1, b2, b3, wp, out);
}